// Round 13
// baseline (395.932 us; speedup 1.0000x reference)
//
#include <hip/hip_runtime.h>

#define DEVFN static __device__ __forceinline__

typedef __attribute__((ext_vector_type(8))) short short8;
typedef __attribute__((ext_vector_type(4))) float f32x4;

#define NB_SCAN 256
#define NB3 256
#define BUCKET 120
#define MAXBUK 2048

DEVFN float leaky(float x) { return x > 0.f ? x : 0.01f * x; }

DEVFN float wsum(float v) {
#pragma unroll
    for (int o = 32; o > 0; o >>= 1) v += __shfl_xor(v, o, 64);
    return v;
}

DEVFN unsigned short f2bf(float f) {
    unsigned u = __float_as_uint(f);
    unsigned r = (u + 0x7FFFu + ((u >> 16) & 1u)) >> 16;
    return (unsigned short)r;
}
DEVFN float bf2f(unsigned short h) { return __uint_as_float(((unsigned)h) << 16); }

// ---------------- P1: bucket histogram (LDS-privatized) ----------------
__global__ void k_bhist(const int* __restrict__ tt_src, const int* __restrict__ tt_dst,
                        const int* __restrict__ dt_dst,
                        int* __restrict__ cnt_d, int* __restrict__ cnt_s, int* __restrict__ cnt_t,
                        int n_tt, int n_dt, int nbuk) {
    __shared__ int h[2 * MAXBUK];
    int blk = blockIdx.x, y = blockIdx.y;
    for (int k = threadIdx.x; k < nbuk; k += 256) {
        h[k] = 0;
        if (y == 0) h[MAXBUK + k] = 0;
    }
    __syncthreads();
    int n = (y == 0) ? n_tt : n_dt;
    int chunk = (n + NB3 - 1) / NB3;
    int e0 = blk * chunk;
    int e1 = e0 + chunk < n ? e0 + chunk : n;
    if (y == 0) {
        for (int i = e0 + threadIdx.x; i < e1; i += 256) {
            unsigned d = (unsigned)tt_dst[i], s = (unsigned)tt_src[i];
            atomicAdd(&h[d / BUCKET], 1);
            atomicAdd(&h[MAXBUK + s / BUCKET], 1);
        }
    } else {
        for (int i = e0 + threadIdx.x; i < e1; i += 256) {
            unsigned d = (unsigned)dt_dst[i];
            atomicAdd(&h[d / BUCKET], 1);
        }
    }
    __syncthreads();
    for (int k = threadIdx.x; k < nbuk; k += 256) {
        if (y == 0) {
            cnt_d[k * NB3 + blk] = h[k];
            cnt_s[k * NB3 + blk] = h[MAXBUK + k];
        } else {
            cnt_t[k * NB3 + blk] = h[k];
        }
    }
}

// ---------------- multi-block scan over 3 arrays via blockIdx.y ----------------
__global__ void k_scanA(const int* __restrict__ d0, const int* __restrict__ d1,
                        const int* __restrict__ d2, int* __restrict__ bsum, int n) {
    const int* deg = blockIdx.y == 0 ? d0 : (blockIdx.y == 1 ? d1 : d2);
    int chunk = (n + NB_SCAN - 1) / NB_SCAN;
    int base = blockIdx.x * chunk;
    int end = base + chunk;
    if (end > n) end = n;
    int s = 0;
    for (int i = base + threadIdx.x; i < end; i += 256) s += deg[i];
    int lane = threadIdx.x & 63, wid = threadIdx.x >> 6;
#pragma unroll
    for (int o = 32; o > 0; o >>= 1) s += __shfl_xor(s, o, 64);
    __shared__ int w[4];
    if (lane == 0) w[wid] = s;
    __syncthreads();
    if (threadIdx.x == 0) bsum[blockIdx.y * NB_SCAN + blockIdx.x] = w[0] + w[1] + w[2] + w[3];
}

// scanC computes its own block prefix from raw bsum (scanB folded in)
__global__ void k_scanC(const int* __restrict__ d0, const int* __restrict__ d1,
                        const int* __restrict__ d2, const int* __restrict__ bsum,
                        int* __restrict__ o0, int* __restrict__ o1, int* __restrict__ o2,
                        int n) {
    const int* deg = blockIdx.y == 0 ? d0 : (blockIdx.y == 1 ? d1 : d2);
    int* off = blockIdx.y == 0 ? o0 : (blockIdx.y == 1 ? o1 : o2);
    __shared__ int bl[NB_SCAN];
    int t = threadIdx.x;
    int bv = bsum[blockIdx.y * NB_SCAN + t];
    bl[t] = bv;
    __syncthreads();
    for (int o = 1; o < NB_SCAN; o <<= 1) {
        int u = (t >= o) ? bl[t - o] : 0;
        __syncthreads();
        bl[t] += u;
        __syncthreads();
    }
    int blockpref = (blockIdx.x > 0) ? bl[blockIdx.x - 1] : 0;
    __syncthreads();

    int chunk = (n + NB_SCAN - 1) / NB_SCAN;
    int base = blockIdx.x * chunk;
    int end = base + chunk;
    if (end > n) end = n;
    int sub = (chunk + 255) >> 8;
    int s0 = base + t * sub;
    int s1 = s0 + sub;
    if (s0 > end) s0 = end;
    if (s1 > end) s1 = end;
    int s = 0;
    for (int i = s0; i < s1; ++i) s += deg[i];
    __shared__ int lds[256];
    lds[t] = s;
    __syncthreads();
    for (int o = 1; o < 256; o <<= 1) {
        int u = (t >= o) ? lds[t - o] : 0;
        __syncthreads();
        lds[t] += u;
        __syncthreads();
    }
    int ex = blockpref + lds[t] - s;
    for (int i = s0; i < s1; ++i) {
        off[i] = ex;
        ex += deg[i];
    }
}

// ---------------- P3: dump edges bucket-grouped, packed (loc<<22 | other) ----------------
__global__ void k_bdump(const int* __restrict__ tt_src, const int* __restrict__ tt_dst,
                        const int* __restrict__ dt_src, const int* __restrict__ dt_dst,
                        const int* __restrict__ base_d, const int* __restrict__ base_s,
                        const int* __restrict__ base_t,
                        unsigned* __restrict__ packed_d, unsigned* __restrict__ packed_s,
                        unsigned* __restrict__ packed_t,
                        int n_tt, int n_dt, int nbuk) {
    __shared__ int cur[2 * MAXBUK];
    int blk = blockIdx.x, y = blockIdx.y;
    for (int k = threadIdx.x; k < nbuk; k += 256) {
        if (y == 0) {
            cur[k] = base_d[k * NB3 + blk];
            cur[MAXBUK + k] = base_s[k * NB3 + blk];
        } else {
            cur[k] = base_t[k * NB3 + blk];
        }
    }
    __syncthreads();
    int n = (y == 0) ? n_tt : n_dt;
    int chunk = (n + NB3 - 1) / NB3;
    int e0 = blk * chunk;
    int e1 = e0 + chunk < n ? e0 + chunk : n;
    if (y == 0) {
        for (int i = e0 + threadIdx.x; i < e1; i += 256) {
            unsigned s = (unsigned)tt_src[i], d = (unsigned)tt_dst[i];
            unsigned bd = d / BUCKET, bs = s / BUCKET;
            int pd = atomicAdd(&cur[bd], 1);
            packed_d[pd] = ((d - bd * BUCKET) << 22) | s;
            int ps = atomicAdd(&cur[MAXBUK + bs], 1);
            packed_s[ps] = ((s - bs * BUCKET) << 22) | d;
        }
    } else {
        for (int i = e0 + threadIdx.x; i < e1; i += 256) {
            unsigned s = (unsigned)dt_src[i], d = (unsigned)dt_dst[i];
            unsigned bd = d / BUCKET;
            int pt = atomicAdd(&cur[bd], 1);
            packed_t[pt] = ((d - bd * BUCKET) << 22) | s;
        }
    }
}

// ---------------- P3b: bucket-local exact CSR (both tt directions via blockIdx.y) --------
__global__ void __launch_bounds__(256) k_bcsr(
    const unsigned* __restrict__ packed_d, const unsigned* __restrict__ packed_s,
    const int* __restrict__ base_d, const int* __restrict__ base_s,
    unsigned* __restrict__ other_d, unsigned* __restrict__ other_s,
    int* __restrict__ off_d, int* __restrict__ off_s,
    int* __restrict__ deg_d, int* __restrict__ deg_s,
    int n_tt, int n_tasks, int nbuk) {
    int y = blockIdx.y;
    const unsigned* packed = y ? packed_s : packed_d;
    const int* bases = y ? base_s : base_d;
    unsigned* other = y ? other_s : other_d;
    int* offo = y ? off_s : off_d;
    int* dego = y ? deg_s : deg_d;
    __shared__ int cnt[128];
    __shared__ int sc[128];
    __shared__ int cur[128];
    int tid = threadIdx.x;
    int b = blockIdx.x;
    int r0 = b * BUCKET;
    int rcount = n_tasks - r0 < BUCKET ? n_tasks - r0 : BUCKET;
    int a0 = bases[b * NB3];
    int a1 = (b + 1 < nbuk) ? bases[(b + 1) * NB3] : n_tt;
    if (tid < 128) cnt[tid] = 0;
    __syncthreads();
    for (int e = a0 + tid; e < a1; e += 256) atomicAdd(&cnt[packed[e] >> 22], 1);
    __syncthreads();
    if (tid < 128) sc[tid] = cnt[tid];
    __syncthreads();
    for (int o = 1; o < 128; o <<= 1) {
        int v = (tid >= o && tid < 128) ? sc[tid - o] : 0;
        __syncthreads();
        if (tid < 128) sc[tid] += v;
        __syncthreads();
    }
    if (tid < 128) {
        int ex = sc[tid] - cnt[tid];
        cur[tid] = ex;
        if (tid < rcount) {
            offo[r0 + tid] = a0 + ex;
            dego[r0 + tid] = cnt[tid];
        }
    }
    if (b == nbuk - 1 && tid == 0) offo[n_tasks] = n_tt;
    __syncthreads();
    for (int e = a0 + tid; e < a1; e += 256) {
        unsigned p = packed[e];
        int dl = p >> 22;
        int pos = atomicAdd(&cur[dl], 1);
        other[(size_t)a0 + pos] = p & 0x3FFFFF;
    }
}

// ---------------- fused dt-agg + fused-linear + LN -> bf16 (block per bucket) ----------
__global__ void k_aggfused(const float* __restrict__ data_x, const unsigned* __restrict__ packed_t,
                           const int* __restrict__ base_t, const float* __restrict__ tasks_x,
                           const float* __restrict__ Wrel, const float* __restrict__ brel,
                           const float* __restrict__ Wroot,
                           const float* __restrict__ g, const float* __restrict__ b,
                           unsigned short* __restrict__ xh, int n_dt, int n_tasks, int nbuk) {
    __shared__ float aggL[BUCKET * 5];
    int bb = blockIdx.x;
    int r0 = bb * BUCKET;
    int rcount = n_tasks - r0 < BUCKET ? n_tasks - r0 : BUCKET;
    for (int k = threadIdx.x; k < BUCKET * 5; k += 256) aggL[k] = 0.f;
    __syncthreads();
    int a0 = base_t[bb * NB3];
    int a1 = (bb + 1 < nbuk) ? base_t[(bb + 1) * NB3] : n_dt;
    for (int e = a0 + threadIdx.x; e < a1; e += 256) {
        unsigned p = packed_t[e];
        int s = p & 0x3FFFFF;
        int dl = p >> 22;
        const float* xp = data_x + (size_t)s * 5;
#pragma unroll
        for (int c = 0; c < 5; ++c) atomicAdd(&aggL[dl * 5 + c], xp[c]);
    }
    __syncthreads();
    int lane = threadIdx.x & 63;
    int w = threadIdx.x >> 6;
    float wrel[5], wroot[12];
#pragma unroll
    for (int k = 0; k < 5; ++k) wrel[k] = Wrel[k * 64 + lane];
#pragma unroll
    for (int k = 0; k < 12; ++k) wroot[k] = Wroot[k * 64 + lane];
    float bj = brel[lane], gj = g[lane], bbj = b[lane];
    for (int lr = w; lr < rcount; lr += 4) {
        int r = r0 + lr;
        float f = bj;
#pragma unroll
        for (int k = 0; k < 5; ++k) f = fmaf(aggL[lr * 5 + k], wrel[k], f);
        const float* tx = tasks_x + (size_t)r * 12;
#pragma unroll
        for (int k = 0; k < 12; ++k) f = fmaf(tx[k], wroot[k], f);
        float m = wsum(f) * 0.015625f;
        float d = f - m;
        float v = wsum(d * d) * 0.015625f;
        float y = fmaf(d * rsqrtf(v + 1e-5f), gj, bbj);
        xh[(size_t)r * 64 + lane] = f2bf(leaky(y));
    }
}

// ---------------- weight fragments (parallelized) + gsum zero ----------------
__global__ void k_prepw(const float* __restrict__ W1d, const float* __restrict__ W2d,
                        const float* __restrict__ W1r, const float* __restrict__ W2r,
                        const float* __restrict__ PW, unsigned short* __restrict__ wf,
                        float* __restrict__ gsum) {
    int lane = threadIdx.x;  // 64
    int r16 = lane & 15, g = lane >> 4;
    int b = blockIdx.x;
    if (b == 0) gsum[lane] = 0.f;
    if (b < 16) {
        int c = b >> 3;
        int tup = b & 7;
        int kk = tup >> 2, nt = tup & 3;
        const float* W1 = c ? W1r : W1d;
        const float* W2 = c ? W2r : W2d;
        unsigned short* out = wf + (size_t)c * 48 * 512;
        int fr = (kk * 4 + nt) * 2;
#pragma unroll
        for (int j = 0; j < 8; ++j) {
            int k = kk * 32 + g * 8 + j, col = nt * 16 + r16;
            float vc = W1[k * 64 + col] - W1[(64 + k) * 64 + col];
            unsigned short hi = f2bf(vc);
            out[(size_t)fr * 512 + lane * 8 + j] = hi;
            out[(size_t)(fr + 1) * 512 + lane * 8 + j] = f2bf(vc - bf2f(hi));
            float vt = W1[(64 + k) * 64 + col];
            hi = f2bf(vt);
            out[(size_t)(16 + fr) * 512 + lane * 8 + j] = hi;
            out[(size_t)(16 + fr + 1) * 512 + lane * 8 + j] = f2bf(vt - bf2f(hi));
            float v2 = W2[k * 64 + col];
            hi = f2bf(v2);
            out[(size_t)(32 + fr) * 512 + lane * 8 + j] = hi;
            out[(size_t)(32 + fr + 1) * 512 + lane * 8 + j] = f2bf(v2 - bf2f(hi));
        }
    } else {
        unsigned short* out = wf + (size_t)96 * 512;
        int t0 = (b - 16) * 4;
        for (int tt = t0; tt < t0 + 4; ++tt) {
            int kk = tt >> 2, nt = tt & 3;
            int fr = (kk * 4 + nt) * 2;
#pragma unroll
            for (int j = 0; j < 8; ++j) {
                int k = kk * 32 + g * 8 + j, col = nt * 16 + r16;
                float v = PW[k * 64 + col];
                unsigned short hi = f2bf(v);
                out[(size_t)fr * 512 + lane * 8 + j] = hi;
                out[(size_t)(fr + 1) * 512 + lane * 8 + j] = f2bf(v - bf2f(hi));
            }
        }
    }
}

// ---------------- C/T GEMM (both convs via blockIdx.y); C and T stored bf16 ----------
__global__ void __launch_bounds__(256, 2) k_ct(
    const unsigned short* __restrict__ xh, const unsigned short* __restrict__ wfall,
    const float* __restrict__ b1d, const float* __restrict__ b1r,
    unsigned short* __restrict__ Hd, unsigned short* __restrict__ Hr,
    unsigned short* __restrict__ Tbd, unsigned short* __restrict__ Tbr,
    int n_rows, int n_tiles) {
    int y = blockIdx.y;
    const unsigned short* wf = wfall + (size_t)y * 48 * 512;
    const float* b1 = y ? b1r : b1d;
    unsigned short* Cb = y ? Hr : Hd;
    unsigned short* Tb = y ? Tbr : Tbd;
    int lane = threadIdx.x & 63;
    int r16 = lane & 15, g = lane >> 4;
    int wave = (blockIdx.x * blockDim.x + threadIdx.x) >> 6;
    int nwaves = (gridDim.x * blockDim.x) >> 6;
    short8 cw[2][4][2], tw[2][4][2];
#pragma unroll
    for (int kk = 0; kk < 2; ++kk)
#pragma unroll
        for (int nt = 0; nt < 4; ++nt)
#pragma unroll
            for (int hl = 0; hl < 2; ++hl) {
                int fr = (kk * 4 + nt) * 2 + hl;
                cw[kk][nt][hl] = *(const short8*)(wf + (size_t)fr * 512 + lane * 8);
                tw[kk][nt][hl] = *(const short8*)(wf + (size_t)(16 + fr) * 512 + lane * 8);
            }
    float b1v[4];
#pragma unroll
    for (int nt = 0; nt < 4; ++nt) b1v[nt] = b1[nt * 16 + r16];
    for (int t = wave; t < n_tiles; t += nwaves) {
        int r0 = t * 16;
        int ra = r0 + r16;
        ra = ra < n_rows ? ra : n_rows - 1;
        short8 af[2];
        af[0] = *(const short8*)(xh + (size_t)ra * 64 + g * 8);
        af[1] = *(const short8*)(xh + (size_t)ra * 64 + 32 + g * 8);
        f32x4 accC[4], accT[4];
#pragma unroll
        for (int nt = 0; nt < 4; ++nt) {
            accC[nt] = (f32x4){b1v[nt], b1v[nt], b1v[nt], b1v[nt]};
            accT[nt] = (f32x4){0.f, 0.f, 0.f, 0.f};
        }
#pragma unroll
        for (int kk = 0; kk < 2; ++kk)
#pragma unroll
            for (int nt = 0; nt < 4; ++nt) {
                accC[nt] = __builtin_amdgcn_mfma_f32_16x16x32_bf16(af[kk], cw[kk][nt][0], accC[nt], 0, 0, 0);
                accC[nt] = __builtin_amdgcn_mfma_f32_16x16x32_bf16(af[kk], cw[kk][nt][1], accC[nt], 0, 0, 0);
                accT[nt] = __builtin_amdgcn_mfma_f32_16x16x32_bf16(af[kk], tw[kk][nt][0], accT[nt], 0, 0, 0);
                accT[nt] = __builtin_amdgcn_mfma_f32_16x16x32_bf16(af[kk], tw[kk][nt][1], accT[nt], 0, 0, 0);
            }
#pragma unroll
        for (int nt = 0; nt < 4; ++nt)
#pragma unroll
            for (int q = 0; q < 4; ++q) {
                int row = r0 + g * 4 + q;
                if (row < n_rows) {
                    Cb[(size_t)row * 64 + nt * 16 + r16] = f2bf(accC[nt][q]);
                    Tb[(size_t)row * 64 + nt * 16 + r16] = f2bf(accT[nt][q]);
                }
            }
    }
}

// ---------------- edge pass: both directions fused per task (independent gather chains) ----
__global__ void k_edge(unsigned short* __restrict__ Hd, unsigned short* __restrict__ Hr,
                       const unsigned short* __restrict__ Tbd, const unsigned short* __restrict__ Tbr,
                       const int* __restrict__ off_d, const int* __restrict__ off_s,
                       const unsigned* __restrict__ other_d, const unsigned* __restrict__ other_s,
                       int n_tasks) {
    int lane = threadIdx.x & 63;
    int wave = (blockIdx.x * blockDim.x + threadIdx.x) >> 6;
    int nwaves = (gridDim.x * blockDim.x) >> 6;
    for (int i = wave; i < n_tasks; i += nwaves) {
        int pd = off_d[i], d1 = off_d[i + 1];
        int ps = off_s[i], s1 = off_s[i + 1];
        float cvd = bf2f(Hd[(size_t)i * 64 + lane]);
        float cvr = bf2f(Hr[(size_t)i * 64 + lane]);
        float accd = 0.f, accr = 0.f;
        while (pd + 2 <= d1 && ps + 2 <= s1) {
            unsigned jd0 = other_d[pd], jd1 = other_d[pd + 1];
            unsigned js0 = other_s[ps], js1 = other_s[ps + 1];
            float td0 = bf2f(Tbd[(size_t)jd0 * 64 + lane]);
            float td1 = bf2f(Tbd[(size_t)jd1 * 64 + lane]);
            float tr0 = bf2f(Tbr[(size_t)js0 * 64 + lane]);
            float tr1 = bf2f(Tbr[(size_t)js1 * 64 + lane]);
            accd += leaky(cvd + td0);
            accd += leaky(cvd + td1);
            accr += leaky(cvr + tr0);
            accr += leaky(cvr + tr1);
            pd += 2;
            ps += 2;
        }
        for (; pd + 4 <= d1; pd += 4) {
            float t0 = bf2f(Tbd[(size_t)other_d[pd] * 64 + lane]);
            float t1 = bf2f(Tbd[(size_t)other_d[pd + 1] * 64 + lane]);
            float t2 = bf2f(Tbd[(size_t)other_d[pd + 2] * 64 + lane]);
            float t3 = bf2f(Tbd[(size_t)other_d[pd + 3] * 64 + lane]);
            accd += leaky(cvd + t0);
            accd += leaky(cvd + t1);
            accd += leaky(cvd + t2);
            accd += leaky(cvd + t3);
        }
        for (; pd < d1; ++pd) accd += leaky(cvd + bf2f(Tbd[(size_t)other_d[pd] * 64 + lane]));
        for (; ps + 4 <= s1; ps += 4) {
            float t0 = bf2f(Tbr[(size_t)other_s[ps] * 64 + lane]);
            float t1 = bf2f(Tbr[(size_t)other_s[ps + 1] * 64 + lane]);
            float t2 = bf2f(Tbr[(size_t)other_s[ps + 2] * 64 + lane]);
            float t3 = bf2f(Tbr[(size_t)other_s[ps + 3] * 64 + lane]);
            accr += leaky(cvr + t0);
            accr += leaky(cvr + t1);
            accr += leaky(cvr + t2);
            accr += leaky(cvr + t3);
        }
        for (; ps < s1; ++ps) accr += leaky(cvr + bf2f(Tbr[(size_t)other_s[ps] * 64 + lane]));
        Hd[(size_t)i * 64 + lane] = f2bf(accd);
        Hr[(size_t)i * 64 + lane] = f2bf(accr);
    }
}

// ---------------- layer-2 GEMM in place (bf16 in/out): H = bf16(H)@W2 + deg*b2 ----------
__global__ void __launch_bounds__(256, 2) k_post(
    unsigned short* __restrict__ Hd, unsigned short* __restrict__ Hr,
    const unsigned short* __restrict__ wfall,
    const float* __restrict__ b2d, const float* __restrict__ b2r,
    const int* __restrict__ deg_d, const int* __restrict__ deg_s,
    int n_rows, int n_tiles) {
    int y = blockIdx.y;
    unsigned short* H = y ? Hr : Hd;
    const unsigned short* wf = wfall + (size_t)(y ? 48 + 32 : 32) * 512;
    const float* b2 = y ? b2r : b2d;
    const int* deg = y ? deg_s : deg_d;
    int lane = threadIdx.x & 63;
    int r16 = lane & 15, g = lane >> 4;
    int wave = (blockIdx.x * blockDim.x + threadIdx.x) >> 6;
    int nwaves = (gridDim.x * blockDim.x) >> 6;
    short8 w2[2][4][2];
#pragma unroll
    for (int kk = 0; kk < 2; ++kk)
#pragma unroll
        for (int nt = 0; nt < 4; ++nt)
#pragma unroll
            for (int hl = 0; hl < 2; ++hl)
                w2[kk][nt][hl] =
                    *(const short8*)(wf + (size_t)((kk * 4 + nt) * 2 + hl) * 512 + lane * 8);
    float b2v[4];
#pragma unroll
    for (int nt = 0; nt < 4; ++nt) b2v[nt] = b2[nt * 16 + r16];
    for (int t = wave; t < n_tiles; t += nwaves) {
        int r0 = t * 16;
        int ra = r0 + r16;
        ra = ra < n_rows ? ra : n_rows - 1;
        short8 af[2];
        af[0] = *(const short8*)(H + (size_t)ra * 64 + g * 8);
        af[1] = *(const short8*)(H + (size_t)ra * 64 + 32 + g * 8);
        float degf[4];
#pragma unroll
        for (int q = 0; q < 4; ++q) {
            int r = r0 + g * 4 + q;
            r = r < n_rows ? r : n_rows - 1;
            degf[q] = (float)deg[r];
        }
        f32x4 acc[4];
#pragma unroll
        for (int nt = 0; nt < 4; ++nt)
#pragma unroll
            for (int q = 0; q < 4; ++q) acc[nt][q] = degf[q] * b2v[nt];
#pragma unroll
        for (int kk = 0; kk < 2; ++kk)
#pragma unroll
            for (int nt = 0; nt < 4; ++nt) {
                acc[nt] = __builtin_amdgcn_mfma_f32_16x16x32_bf16(af[kk], w2[kk][nt][0], acc[nt], 0, 0, 0);
                acc[nt] = __builtin_amdgcn_mfma_f32_16x16x32_bf16(af[kk], w2[kk][nt][1], acc[nt], 0, 0, 0);
            }
#pragma unroll
        for (int nt = 0; nt < 4; ++nt)
#pragma unroll
            for (int q = 0; q < 4; ++q) {
                int row = r0 + g * 4 + q;
                if (row < n_rows) H[(size_t)row * 64 + nt * 16 + r16] = f2bf(acc[nt][q]);
            }
    }
}

// ---------------- finalize (MFMA): LN+leaky both convs (bf16 in), proj, gsum, candidate ----
__global__ void __launch_bounds__(256, 2) k_finalize(
    const unsigned short* __restrict__ dep_raw, const unsigned short* __restrict__ rev_raw,
    const float* __restrict__ dg, const float* __restrict__ db,
    const float* __restrict__ rg, const float* __restrict__ rb,
    const unsigned short* __restrict__ pwf, const float* __restrict__ pb,
    float* __restrict__ out, float* __restrict__ gsum, int n_rows, int n_tiles) {
    __shared__ float red[4][64];
    int lane = threadIdx.x & 63;
    int wid = threadIdx.x >> 6;
    int r16 = lane & 15, g = lane >> 4;
    int wave = (blockIdx.x * blockDim.x + threadIdx.x) >> 6;
    int nwaves = (gridDim.x * blockDim.x) >> 6;

    short8 wf[4][4][2];
#pragma unroll
    for (int kk = 0; kk < 4; ++kk)
#pragma unroll
        for (int nt = 0; nt < 4; ++nt)
#pragma unroll
            for (int hl = 0; hl < 2; ++hl)
                wf[kk][nt][hl] =
                    *(const short8*)(pwf + (size_t)((kk * 4 + nt) * 2 + hl) * 512 + lane * 8);

    f32x4 gd0 = *(const f32x4*)(dg + g * 8), gd1 = *(const f32x4*)(dg + g * 8 + 4);
    f32x4 gd2 = *(const f32x4*)(dg + 32 + g * 8), gd3 = *(const f32x4*)(dg + 32 + g * 8 + 4);
    f32x4 bd0 = *(const f32x4*)(db + g * 8), bd1 = *(const f32x4*)(db + g * 8 + 4);
    f32x4 bd2 = *(const f32x4*)(db + 32 + g * 8), bd3 = *(const f32x4*)(db + 32 + g * 8 + 4);
    f32x4 gr0 = *(const f32x4*)(rg + g * 8), gr1 = *(const f32x4*)(rg + g * 8 + 4);
    f32x4 gr2 = *(const f32x4*)(rg + 32 + g * 8), gr3 = *(const f32x4*)(rg + 32 + g * 8 + 4);
    f32x4 br0 = *(const f32x4*)(rb + g * 8), br1 = *(const f32x4*)(rb + g * 8 + 4);
    f32x4 br2 = *(const f32x4*)(rb + 32 + g * 8), br3 = *(const f32x4*)(rb + 32 + g * 8 + 4);

    float b2v[4];
#pragma unroll
    for (int nt = 0; nt < 4; ++nt) b2v[nt] = pb[nt * 16 + r16];
    float gacc[4] = {0.f, 0.f, 0.f, 0.f};

    for (int t = wave; t < n_tiles; t += nwaves) {
        int r0 = t * 16;
        int ra = r0 + r16;
        ra = ra < n_rows ? ra : n_rows - 1;
        const unsigned short* dp = dep_raw + (size_t)ra * 64;
        const unsigned short* rp = rev_raw + (size_t)ra * 64;
        short8 hd0 = *(const short8*)(dp + g * 8);
        short8 hd1 = *(const short8*)(dp + 32 + g * 8);
        short8 hr0 = *(const short8*)(rp + g * 8);
        short8 hr1 = *(const short8*)(rp + 32 + g * 8);
        f32x4 xd0, xd1, xd2, xd3, xr0, xr1, xr2, xr3;
#pragma unroll
        for (int j = 0; j < 4; ++j) {
            xd0[j] = bf2f((unsigned short)hd0[j]);
            xd1[j] = bf2f((unsigned short)hd0[4 + j]);
            xd2[j] = bf2f((unsigned short)hd1[j]);
            xd3[j] = bf2f((unsigned short)hd1[4 + j]);
            xr0[j] = bf2f((unsigned short)hr0[j]);
            xr1[j] = bf2f((unsigned short)hr0[4 + j]);
            xr2[j] = bf2f((unsigned short)hr1[j]);
            xr3[j] = bf2f((unsigned short)hr1[4 + j]);
        }

        float sd = 0.f, qd = 0.f, sr = 0.f, qr = 0.f;
#pragma unroll
        for (int j = 0; j < 4; ++j) {
            sd += xd0[j] + xd1[j] + xd2[j] + xd3[j];
            qd = fmaf(xd0[j], xd0[j], qd); qd = fmaf(xd1[j], xd1[j], qd);
            qd = fmaf(xd2[j], xd2[j], qd); qd = fmaf(xd3[j], xd3[j], qd);
            sr += xr0[j] + xr1[j] + xr2[j] + xr3[j];
            qr = fmaf(xr0[j], xr0[j], qr); qr = fmaf(xr1[j], xr1[j], qr);
            qr = fmaf(xr2[j], xr2[j], qr); qr = fmaf(xr3[j], xr3[j], qr);
        }
#pragma unroll
        for (int o = 16; o <= 32; o <<= 1) {
            sd += __shfl_xor(sd, o, 64); qd += __shfl_xor(qd, o, 64);
            sr += __shfl_xor(sr, o, 64); qr += __shfl_xor(qr, o, 64);
        }
        float md = sd * 0.015625f;
        float rstd_d = rsqrtf(fmaf(qd, 0.015625f, -md * md) + 1e-5f);
        float mr = sr * 0.015625f;
        float rstd_r = rsqrtf(fmaf(qr, 0.015625f, -mr * mr) + 1e-5f);

        short8 af[4];
#pragma unroll
        for (int j = 0; j < 4; ++j) {
            af[0][j]     = (short)f2bf(leaky(fmaf((xd0[j] - md) * rstd_d, gd0[j], bd0[j])));
            af[0][4 + j] = (short)f2bf(leaky(fmaf((xd1[j] - md) * rstd_d, gd1[j], bd1[j])));
            af[1][j]     = (short)f2bf(leaky(fmaf((xd2[j] - md) * rstd_d, gd2[j], bd2[j])));
            af[1][4 + j] = (short)f2bf(leaky(fmaf((xd3[j] - md) * rstd_d, gd3[j], bd3[j])));
            af[2][j]     = (short)f2bf(leaky(fmaf((xr0[j] - mr) * rstd_r, gr0[j], br0[j])));
            af[2][4 + j] = (short)f2bf(leaky(fmaf((xr1[j] - mr) * rstd_r, gr1[j], br1[j])));
            af[3][j]     = (short)f2bf(leaky(fmaf((xr2[j] - mr) * rstd_r, gr2[j], br2[j])));
            af[3][4 + j] = (short)f2bf(leaky(fmaf((xr3[j] - mr) * rstd_r, gr3[j], br3[j])));
        }

        f32x4 acc[4];
#pragma unroll
        for (int nt = 0; nt < 4; ++nt) acc[nt] = (f32x4){b2v[nt], b2v[nt], b2v[nt], b2v[nt]};
#pragma unroll
        for (int kk = 0; kk < 4; ++kk)
#pragma unroll
            for (int nt = 0; nt < 4; ++nt) {
                acc[nt] = __builtin_amdgcn_mfma_f32_16x16x32_bf16(af[kk], wf[kk][nt][0], acc[nt], 0, 0, 0);
                acc[nt] = __builtin_amdgcn_mfma_f32_16x16x32_bf16(af[kk], wf[kk][nt][1], acc[nt], 0, 0, 0);
            }
#pragma unroll
        for (int nt = 0; nt < 4; ++nt)
#pragma unroll
            for (int q = 0; q < 4; ++q) {
                float tf = leaky(acc[nt][q]);
                int grow = r0 + g * 4 + q;
                if (grow < n_rows) gacc[nt] += tf;
                if (grow == 0) out[64 + nt * 16 + r16] = tf;
            }
    }
#pragma unroll
    for (int nt = 0; nt < 4; ++nt) {
        gacc[nt] += __shfl_xor(gacc[nt], 16, 64);
        gacc[nt] += __shfl_xor(gacc[nt], 32, 64);
    }
    if (g == 0) {
#pragma unroll
        for (int nt = 0; nt < 4; ++nt) red[wid][nt * 16 + r16] = gacc[nt];
    }
    __syncthreads();
    if (threadIdx.x < 64) {
        float ssum = red[0][threadIdx.x] + red[1][threadIdx.x] +
                     red[2][threadIdx.x] + red[3][threadIdx.x];
        atomicAdd(&gsum[threadIdx.x], ssum);
    }
}

// ---------------- tail ----------------
__global__ void k_tail(const float* __restrict__ gsum, const int* __restrict__ counts,
                       const float* __restrict__ devx, const float* __restrict__ timex,
                       const float* __restrict__ dW, const float* __restrict__ dB,
                       float* __restrict__ out) {
    int j = threadIdx.x;
    if (j >= 64) return;
    int c = counts[0];
    if (c < 1) c = 1;
    out[j] = gsum[j] / (float)c;
    float t = timex[0] * 1e-5f;
    float acc = dB[j];
    for (int k = 0; k < 96; ++k) acc = fmaf(devx[k], dW[k * 64 + j], acc);
    acc = fmaf(t, dW[96 * 64 + j], acc);
    out[128 + j] = leaky(acc);
}

extern "C" void kernel_launch(void* const* d_in, const int* in_sizes, int n_in,
                              void* d_out, int out_size, void* d_ws, size_t ws_size,
                              hipStream_t stream) {
    const float* data_x    = (const float*)d_in[0];
    const float* tasks_x   = (const float*)d_in[1];
    const float* devices_x = (const float*)d_in[2];
    const float* time_x    = (const float*)d_in[3];
    const int*   dt_src    = (const int*)d_in[4];
    const int*   dt_dst    = (const int*)d_in[5];
    const int*   tt_src    = (const int*)d_in[6];
    const int*   tt_dst    = (const int*)d_in[7];
    const int*   counts    = (const int*)d_in[8];
    const float* gc_W_rel  = (const float*)d_in[9];
    const float* gc_b_rel  = (const float*)d_in[10];
    const float* gc_W_root = (const float*)d_in[11];
    const float* gc_ln_g   = (const float*)d_in[12];
    const float* gc_ln_b   = (const float*)d_in[13];
    const float* dep_W1    = (const float*)d_in[14];
    const float* dep_b1    = (const float*)d_in[15];
    const float* dep_W2    = (const float*)d_in[16];
    const float* dep_b2    = (const float*)d_in[17];
    const float* dep_ln_g  = (const float*)d_in[18];
    const float* dep_ln_b  = (const float*)d_in[19];
    const float* rev_W1    = (const float*)d_in[20];
    const float* rev_b1    = (const float*)d_in[21];
    const float* rev_W2    = (const float*)d_in[22];
    const float* rev_b2    = (const float*)d_in[23];
    const float* rev_ln_g  = (const float*)d_in[24];
    const float* rev_ln_b  = (const float*)d_in[25];
    const float* dev_W     = (const float*)d_in[26];
    const float* dev_b     = (const float*)d_in[27];
    const float* proj_W    = (const float*)d_in[28];
    const float* proj_b    = (const float*)d_in[29];

    int n_tasks = in_sizes[1] / 12;
    int n_dt = in_sizes[4];
    int n_tt = in_sizes[6];
    int n_tiles = (n_tasks + 15) / 16;
    int nbuk = (n_tasks + BUCKET - 1) / BUCKET;
    int nscan = nbuk * NB3;

    char* ws = (char*)d_ws;
    size_t off = 0;
    auto alloc = [&](size_t bytes) {
        char* p = ws + off;
        off += (bytes + 255) & ~(size_t)255;
        return p;
    };
    unsigned short* xh    = (unsigned short*)alloc((size_t)n_tasks * 64 * 2);
    unsigned short* Hd    = (unsigned short*)alloc((size_t)n_tasks * 64 * 2);
    unsigned short* Hr    = (unsigned short*)alloc((size_t)n_tasks * 64 * 2);
    unsigned short* Tbd   = (unsigned short*)alloc((size_t)n_tasks * 64 * 2);
    unsigned short* Tbr   = (unsigned short*)alloc((size_t)n_tasks * 64 * 2);
    int* cnt_d            = (int*)alloc((size_t)nscan * 4);
    int* cnt_s            = (int*)alloc((size_t)nscan * 4);
    int* cnt_t            = (int*)alloc((size_t)nscan * 4);
    int* base_d           = (int*)alloc((size_t)nscan * 4);
    int* base_s           = (int*)alloc((size_t)nscan * 4);
    int* base_t           = (int*)alloc((size_t)nscan * 4);
    unsigned* packed_d    = (unsigned*)alloc((size_t)n_tt * 4);
    unsigned* packed_s    = (unsigned*)alloc((size_t)n_tt * 4);
    unsigned* packed_t    = (unsigned*)alloc((size_t)n_dt * 4);
    unsigned* other_d     = (unsigned*)alloc((size_t)n_tt * 4);
    unsigned* other_s     = (unsigned*)alloc((size_t)n_tt * 4);
    int* off_d            = (int*)alloc(((size_t)n_tasks + 1) * 4);
    int* off_s            = (int*)alloc(((size_t)n_tasks + 1) * 4);
    int* deg_d            = (int*)alloc((size_t)n_tasks * 4);
    int* deg_s            = (int*)alloc((size_t)n_tasks * 4);
    int* bsum             = (int*)alloc(3 * NB_SCAN * 4);
    float* gsum           = (float*)alloc(64 * 4);
    unsigned short* wfrag = (unsigned short*)alloc((size_t)128 * 512 * 2);

    k_prepw<<<20, 64, 0, stream>>>(dep_W1, dep_W2, rev_W1, rev_W2, proj_W, wfrag, gsum);

    k_bhist<<<dim3(NB3, 2), 256, 0, stream>>>(tt_src, tt_dst, dt_dst,
                                              cnt_d, cnt_s, cnt_t, n_tt, n_dt, nbuk);
    k_scanA<<<dim3(NB_SCAN, 3), 256, 0, stream>>>(cnt_d, cnt_s, cnt_t, bsum, nscan);
    k_scanC<<<dim3(NB_SCAN, 3), 256, 0, stream>>>(cnt_d, cnt_s, cnt_t, bsum,
                                                  base_d, base_s, base_t, nscan);
    k_bdump<<<dim3(NB3, 2), 256, 0, stream>>>(tt_src, tt_dst, dt_src, dt_dst,
                                              base_d, base_s, base_t,
                                              packed_d, packed_s, packed_t, n_tt, n_dt, nbuk);
    k_bcsr<<<dim3(nbuk, 2), 256, 0, stream>>>(packed_d, packed_s, base_d, base_s,
                                              other_d, other_s, off_d, off_s,
                                              deg_d, deg_s, n_tt, n_tasks, nbuk);

    k_aggfused<<<nbuk, 256, 0, stream>>>(data_x, packed_t, base_t, tasks_x,
                                         gc_W_rel, gc_b_rel, gc_W_root,
                                         gc_ln_g, gc_ln_b, xh, n_dt, n_tasks, nbuk);

    k_ct<<<dim3(2048, 2), 256, 0, stream>>>(xh, wfrag, dep_b1, rev_b1, Hd, Hr, Tbd, Tbr,
                                            n_tasks, n_tiles);
    k_edge<<<4096, 256, 0, stream>>>(Hd, Hr, Tbd, Tbr, off_d, off_s,
                                     other_d, other_s, n_tasks);
    k_post<<<dim3(2048, 2), 256, 0, stream>>>(Hd, Hr, wfrag, dep_b2, rev_b2,
                                              deg_d, deg_s, n_tasks, n_tiles);

    k_finalize<<<2048, 256, 0, stream>>>(Hd, Hr, dep_ln_g, dep_ln_b,
                                         rev_ln_g, rev_ln_b, wfrag + (size_t)96 * 512, proj_b,
                                         (float*)d_out, gsum, n_tasks, n_tiles);
    k_tail<<<1, 64, 0, stream>>>(gsum, counts, devices_x, time_x, dev_W, dev_b, (float*)d_out);
}

// Round 14
// 380.278 us; speedup vs baseline: 1.0412x; 1.0412x over previous
//
#include <hip/hip_runtime.h>

#define DEVFN static __device__ __forceinline__

typedef __attribute__((ext_vector_type(8))) short short8;
typedef __attribute__((ext_vector_type(4))) float f32x4;

#define NB_SCAN 256
#define NB3 64
#define BUCKET 120
#define MAXBUK 2048

DEVFN float leaky(float x) { return x > 0.f ? x : 0.01f * x; }

DEVFN float wsum(float v) {
#pragma unroll
    for (int o = 32; o > 0; o >>= 1) v += __shfl_xor(v, o, 64);
    return v;
}

DEVFN unsigned short f2bf(float f) {
    unsigned u = __float_as_uint(f);
    unsigned r = (u + 0x7FFFu + ((u >> 16) & 1u)) >> 16;
    return (unsigned short)r;
}
DEVFN float bf2f(unsigned short h) { return __uint_as_float(((unsigned)h) << 16); }

// ---------------- P1: bucket histogram (LDS-privatized) ----------------
__global__ void k_bhist(const int* __restrict__ tt_src, const int* __restrict__ tt_dst,
                        const int* __restrict__ dt_dst,
                        int* __restrict__ cnt_d, int* __restrict__ cnt_s, int* __restrict__ cnt_t,
                        int n_tt, int n_dt, int nbuk) {
    __shared__ int h[2 * MAXBUK];
    int blk = blockIdx.x, y = blockIdx.y;
    for (int k = threadIdx.x; k < nbuk; k += 256) {
        h[k] = 0;
        if (y == 0) h[MAXBUK + k] = 0;
    }
    __syncthreads();
    int n = (y == 0) ? n_tt : n_dt;
    int chunk = (n + NB3 - 1) / NB3;
    int e0 = blk * chunk;
    int e1 = e0 + chunk < n ? e0 + chunk : n;
    if (y == 0) {
        for (int i = e0 + threadIdx.x; i < e1; i += 256) {
            unsigned d = (unsigned)tt_dst[i], s = (unsigned)tt_src[i];
            atomicAdd(&h[d / BUCKET], 1);
            atomicAdd(&h[MAXBUK + s / BUCKET], 1);
        }
    } else {
        for (int i = e0 + threadIdx.x; i < e1; i += 256) {
            unsigned d = (unsigned)dt_dst[i];
            atomicAdd(&h[d / BUCKET], 1);
        }
    }
    __syncthreads();
    for (int k = threadIdx.x; k < nbuk; k += 256) {
        if (y == 0) {
            cnt_d[k * NB3 + blk] = h[k];
            cnt_s[k * NB3 + blk] = h[MAXBUK + k];
        } else {
            cnt_t[k * NB3 + blk] = h[k];
        }
    }
}

// ---------------- multi-block scan over 3 arrays via blockIdx.y ----------------
__global__ void k_scanA(const int* __restrict__ d0, const int* __restrict__ d1,
                        const int* __restrict__ d2, int* __restrict__ bsum, int n) {
    const int* deg = blockIdx.y == 0 ? d0 : (blockIdx.y == 1 ? d1 : d2);
    int chunk = (n + NB_SCAN - 1) / NB_SCAN;
    int base = blockIdx.x * chunk;
    int end = base + chunk;
    if (end > n) end = n;
    int s = 0;
    for (int i = base + threadIdx.x; i < end; i += 256) s += deg[i];
    int lane = threadIdx.x & 63, wid = threadIdx.x >> 6;
#pragma unroll
    for (int o = 32; o > 0; o >>= 1) s += __shfl_xor(s, o, 64);
    __shared__ int w[4];
    if (lane == 0) w[wid] = s;
    __syncthreads();
    if (threadIdx.x == 0) bsum[blockIdx.y * NB_SCAN + blockIdx.x] = w[0] + w[1] + w[2] + w[3];
}

// scanC computes its own block prefix from raw bsum (scanB folded in)
__global__ void k_scanC(const int* __restrict__ d0, const int* __restrict__ d1,
                        const int* __restrict__ d2, const int* __restrict__ bsum,
                        int* __restrict__ o0, int* __restrict__ o1, int* __restrict__ o2,
                        int n) {
    const int* deg = blockIdx.y == 0 ? d0 : (blockIdx.y == 1 ? d1 : d2);
    int* off = blockIdx.y == 0 ? o0 : (blockIdx.y == 1 ? o1 : o2);
    __shared__ int bl[NB_SCAN];
    int t = threadIdx.x;
    int bv = bsum[blockIdx.y * NB_SCAN + t];
    bl[t] = bv;
    __syncthreads();
    for (int o = 1; o < NB_SCAN; o <<= 1) {
        int u = (t >= o) ? bl[t - o] : 0;
        __syncthreads();
        bl[t] += u;
        __syncthreads();
    }
    int blockpref = (blockIdx.x > 0) ? bl[blockIdx.x - 1] : 0;
    __syncthreads();

    int chunk = (n + NB_SCAN - 1) / NB_SCAN;
    int base = blockIdx.x * chunk;
    int end = base + chunk;
    if (end > n) end = n;
    int sub = (chunk + 255) >> 8;
    int s0 = base + t * sub;
    int s1 = s0 + sub;
    if (s0 > end) s0 = end;
    if (s1 > end) s1 = end;
    int s = 0;
    for (int i = s0; i < s1; ++i) s += deg[i];
    __shared__ int lds[256];
    lds[t] = s;
    __syncthreads();
    for (int o = 1; o < 256; o <<= 1) {
        int u = (t >= o) ? lds[t - o] : 0;
        __syncthreads();
        lds[t] += u;
        __syncthreads();
    }
    int ex = blockpref + lds[t] - s;
    for (int i = s0; i < s1; ++i) {
        off[i] = ex;
        ex += deg[i];
    }
}

// ---------------- P3: dump edges bucket-grouped, packed (loc<<22 | other) ----------------
__global__ void k_bdump(const int* __restrict__ tt_src, const int* __restrict__ tt_dst,
                        const int* __restrict__ dt_src, const int* __restrict__ dt_dst,
                        const int* __restrict__ base_d, const int* __restrict__ base_s,
                        const int* __restrict__ base_t,
                        unsigned* __restrict__ packed_d, unsigned* __restrict__ packed_s,
                        unsigned* __restrict__ packed_t,
                        int n_tt, int n_dt, int nbuk) {
    __shared__ int cur[2 * MAXBUK];
    int blk = blockIdx.x, y = blockIdx.y;
    for (int k = threadIdx.x; k < nbuk; k += 256) {
        if (y == 0) {
            cur[k] = base_d[k * NB3 + blk];
            cur[MAXBUK + k] = base_s[k * NB3 + blk];
        } else {
            cur[k] = base_t[k * NB3 + blk];
        }
    }
    __syncthreads();
    int n = (y == 0) ? n_tt : n_dt;
    int chunk = (n + NB3 - 1) / NB3;
    int e0 = blk * chunk;
    int e1 = e0 + chunk < n ? e0 + chunk : n;
    if (y == 0) {
        for (int i = e0 + threadIdx.x; i < e1; i += 256) {
            unsigned s = (unsigned)tt_src[i], d = (unsigned)tt_dst[i];
            unsigned bd = d / BUCKET, bs = s / BUCKET;
            int pd = atomicAdd(&cur[bd], 1);
            packed_d[pd] = ((d - bd * BUCKET) << 22) | s;
            int ps = atomicAdd(&cur[MAXBUK + bs], 1);
            packed_s[ps] = ((s - bs * BUCKET) << 22) | d;
        }
    } else {
        for (int i = e0 + threadIdx.x; i < e1; i += 256) {
            unsigned s = (unsigned)dt_src[i], d = (unsigned)dt_dst[i];
            unsigned bd = d / BUCKET;
            int pt = atomicAdd(&cur[bd], 1);
            packed_t[pt] = ((d - bd * BUCKET) << 22) | s;
        }
    }
}

// ---------------- P3b: bucket-local exact CSR (both tt directions via blockIdx.y) --------
__global__ void __launch_bounds__(256) k_bcsr(
    const unsigned* __restrict__ packed_d, const unsigned* __restrict__ packed_s,
    const int* __restrict__ base_d, const int* __restrict__ base_s,
    unsigned* __restrict__ other_d, unsigned* __restrict__ other_s,
    int* __restrict__ off_d, int* __restrict__ off_s,
    int* __restrict__ deg_d, int* __restrict__ deg_s,
    int n_tt, int n_tasks, int nbuk) {
    int y = blockIdx.y;
    const unsigned* packed = y ? packed_s : packed_d;
    const int* bases = y ? base_s : base_d;
    unsigned* other = y ? other_s : other_d;
    int* offo = y ? off_s : off_d;
    int* dego = y ? deg_s : deg_d;
    __shared__ int cnt[128];
    __shared__ int sc[128];
    __shared__ int cur[128];
    int tid = threadIdx.x;
    int b = blockIdx.x;
    int r0 = b * BUCKET;
    int rcount = n_tasks - r0 < BUCKET ? n_tasks - r0 : BUCKET;
    int a0 = bases[b * NB3];
    int a1 = (b + 1 < nbuk) ? bases[(b + 1) * NB3] : n_tt;
    if (tid < 128) cnt[tid] = 0;
    __syncthreads();
    for (int e = a0 + tid; e < a1; e += 256) atomicAdd(&cnt[packed[e] >> 22], 1);
    __syncthreads();
    if (tid < 128) sc[tid] = cnt[tid];
    __syncthreads();
    for (int o = 1; o < 128; o <<= 1) {
        int v = (tid >= o && tid < 128) ? sc[tid - o] : 0;
        __syncthreads();
        if (tid < 128) sc[tid] += v;
        __syncthreads();
    }
    if (tid < 128) {
        int ex = sc[tid] - cnt[tid];
        cur[tid] = ex;
        if (tid < rcount) {
            offo[r0 + tid] = a0 + ex;
            dego[r0 + tid] = cnt[tid];
        }
    }
    if (b == nbuk - 1 && tid == 0) offo[n_tasks] = n_tt;
    __syncthreads();
    for (int e = a0 + tid; e < a1; e += 256) {
        unsigned p = packed[e];
        int dl = p >> 22;
        int pos = atomicAdd(&cur[dl], 1);
        other[(size_t)a0 + pos] = p & 0x3FFFFF;
    }
}

// ---------------- fused dt-agg + fused-linear + LN -> bf16 (block per bucket) ----------
__global__ void k_aggfused(const float* __restrict__ data_x, const unsigned* __restrict__ packed_t,
                           const int* __restrict__ base_t, const float* __restrict__ tasks_x,
                           const float* __restrict__ Wrel, const float* __restrict__ brel,
                           const float* __restrict__ Wroot,
                           const float* __restrict__ g, const float* __restrict__ b,
                           unsigned short* __restrict__ xh, int n_dt, int n_tasks, int nbuk) {
    __shared__ float aggL[BUCKET * 5];
    int bb = blockIdx.x;
    int r0 = bb * BUCKET;
    int rcount = n_tasks - r0 < BUCKET ? n_tasks - r0 : BUCKET;
    for (int k = threadIdx.x; k < BUCKET * 5; k += 256) aggL[k] = 0.f;
    __syncthreads();
    int a0 = base_t[bb * NB3];
    int a1 = (bb + 1 < nbuk) ? base_t[(bb + 1) * NB3] : n_dt;
    for (int e = a0 + threadIdx.x; e < a1; e += 256) {
        unsigned p = packed_t[e];
        int s = p & 0x3FFFFF;
        int dl = p >> 22;
        const float* xp = data_x + (size_t)s * 5;
#pragma unroll
        for (int c = 0; c < 5; ++c) atomicAdd(&aggL[dl * 5 + c], xp[c]);
    }
    __syncthreads();
    int lane = threadIdx.x & 63;
    int w = threadIdx.x >> 6;
    float wrel[5], wroot[12];
#pragma unroll
    for (int k = 0; k < 5; ++k) wrel[k] = Wrel[k * 64 + lane];
#pragma unroll
    for (int k = 0; k < 12; ++k) wroot[k] = Wroot[k * 64 + lane];
    float bj = brel[lane], gj = g[lane], bbj = b[lane];
    for (int lr = w; lr < rcount; lr += 4) {
        int r = r0 + lr;
        float f = bj;
#pragma unroll
        for (int k = 0; k < 5; ++k) f = fmaf(aggL[lr * 5 + k], wrel[k], f);
        const float* tx = tasks_x + (size_t)r * 12;
#pragma unroll
        for (int k = 0; k < 12; ++k) f = fmaf(tx[k], wroot[k], f);
        float m = wsum(f) * 0.015625f;
        float d = f - m;
        float v = wsum(d * d) * 0.015625f;
        float y = fmaf(d * rsqrtf(v + 1e-5f), gj, bbj);
        xh[(size_t)r * 64 + lane] = f2bf(leaky(y));
    }
}

// ---------------- weight fragments (parallelized) + gsum zero ----------------
__global__ void k_prepw(const float* __restrict__ W1d, const float* __restrict__ W2d,
                        const float* __restrict__ W1r, const float* __restrict__ W2r,
                        const float* __restrict__ PW, unsigned short* __restrict__ wf,
                        float* __restrict__ gsum) {
    int lane = threadIdx.x;  // 64
    int r16 = lane & 15, g = lane >> 4;
    int b = blockIdx.x;
    if (b == 0) gsum[lane] = 0.f;
    if (b < 16) {
        int c = b >> 3;
        int tup = b & 7;
        int kk = tup >> 2, nt = tup & 3;
        const float* W1 = c ? W1r : W1d;
        const float* W2 = c ? W2r : W2d;
        unsigned short* out = wf + (size_t)c * 48 * 512;
        int fr = (kk * 4 + nt) * 2;
#pragma unroll
        for (int j = 0; j < 8; ++j) {
            int k = kk * 32 + g * 8 + j, col = nt * 16 + r16;
            float vc = W1[k * 64 + col] - W1[(64 + k) * 64 + col];
            unsigned short hi = f2bf(vc);
            out[(size_t)fr * 512 + lane * 8 + j] = hi;
            out[(size_t)(fr + 1) * 512 + lane * 8 + j] = f2bf(vc - bf2f(hi));
            float vt = W1[(64 + k) * 64 + col];
            hi = f2bf(vt);
            out[(size_t)(16 + fr) * 512 + lane * 8 + j] = hi;
            out[(size_t)(16 + fr + 1) * 512 + lane * 8 + j] = f2bf(vt - bf2f(hi));
            float v2 = W2[k * 64 + col];
            hi = f2bf(v2);
            out[(size_t)(32 + fr) * 512 + lane * 8 + j] = hi;
            out[(size_t)(32 + fr + 1) * 512 + lane * 8 + j] = f2bf(v2 - bf2f(hi));
        }
    } else {
        unsigned short* out = wf + (size_t)96 * 512;
        int t0 = (b - 16) * 4;
        for (int tt = t0; tt < t0 + 4; ++tt) {
            int kk = tt >> 2, nt = tt & 3;
            int fr = (kk * 4 + nt) * 2;
#pragma unroll
            for (int j = 0; j < 8; ++j) {
                int k = kk * 32 + g * 8 + j, col = nt * 16 + r16;
                float v = PW[k * 64 + col];
                unsigned short hi = f2bf(v);
                out[(size_t)fr * 512 + lane * 8 + j] = hi;
                out[(size_t)(fr + 1) * 512 + lane * 8 + j] = f2bf(v - bf2f(hi));
            }
        }
    }
}

// ---------------- C/T GEMM (both convs via blockIdx.y); C and T stored bf16 ----------
__global__ void __launch_bounds__(256, 2) k_ct(
    const unsigned short* __restrict__ xh, const unsigned short* __restrict__ wfall,
    const float* __restrict__ b1d, const float* __restrict__ b1r,
    unsigned short* __restrict__ Hd, unsigned short* __restrict__ Hr,
    unsigned short* __restrict__ Tbd, unsigned short* __restrict__ Tbr,
    int n_rows, int n_tiles) {
    int y = blockIdx.y;
    const unsigned short* wf = wfall + (size_t)y * 48 * 512;
    const float* b1 = y ? b1r : b1d;
    unsigned short* Cb = y ? Hr : Hd;
    unsigned short* Tb = y ? Tbr : Tbd;
    int lane = threadIdx.x & 63;
    int r16 = lane & 15, g = lane >> 4;
    int wave = (blockIdx.x * blockDim.x + threadIdx.x) >> 6;
    int nwaves = (gridDim.x * blockDim.x) >> 6;
    short8 cw[2][4][2], tw[2][4][2];
#pragma unroll
    for (int kk = 0; kk < 2; ++kk)
#pragma unroll
        for (int nt = 0; nt < 4; ++nt)
#pragma unroll
            for (int hl = 0; hl < 2; ++hl) {
                int fr = (kk * 4 + nt) * 2 + hl;
                cw[kk][nt][hl] = *(const short8*)(wf + (size_t)fr * 512 + lane * 8);
                tw[kk][nt][hl] = *(const short8*)(wf + (size_t)(16 + fr) * 512 + lane * 8);
            }
    float b1v[4];
#pragma unroll
    for (int nt = 0; nt < 4; ++nt) b1v[nt] = b1[nt * 16 + r16];
    for (int t = wave; t < n_tiles; t += nwaves) {
        int r0 = t * 16;
        int ra = r0 + r16;
        ra = ra < n_rows ? ra : n_rows - 1;
        short8 af[2];
        af[0] = *(const short8*)(xh + (size_t)ra * 64 + g * 8);
        af[1] = *(const short8*)(xh + (size_t)ra * 64 + 32 + g * 8);
        f32x4 accC[4], accT[4];
#pragma unroll
        for (int nt = 0; nt < 4; ++nt) {
            accC[nt] = (f32x4){b1v[nt], b1v[nt], b1v[nt], b1v[nt]};
            accT[nt] = (f32x4){0.f, 0.f, 0.f, 0.f};
        }
#pragma unroll
        for (int kk = 0; kk < 2; ++kk)
#pragma unroll
            for (int nt = 0; nt < 4; ++nt) {
                accC[nt] = __builtin_amdgcn_mfma_f32_16x16x32_bf16(af[kk], cw[kk][nt][0], accC[nt], 0, 0, 0);
                accC[nt] = __builtin_amdgcn_mfma_f32_16x16x32_bf16(af[kk], cw[kk][nt][1], accC[nt], 0, 0, 0);
                accT[nt] = __builtin_amdgcn_mfma_f32_16x16x32_bf16(af[kk], tw[kk][nt][0], accT[nt], 0, 0, 0);
                accT[nt] = __builtin_amdgcn_mfma_f32_16x16x32_bf16(af[kk], tw[kk][nt][1], accT[nt], 0, 0, 0);
            }
#pragma unroll
        for (int nt = 0; nt < 4; ++nt)
#pragma unroll
            for (int q = 0; q < 4; ++q) {
                int row = r0 + g * 4 + q;
                if (row < n_rows) {
                    Cb[(size_t)row * 64 + nt * 16 + r16] = f2bf(accC[nt][q]);
                    Tb[(size_t)row * 64 + nt * 16 + r16] = f2bf(accT[nt][q]);
                }
            }
    }
}

// ---------------- edge pass: both directions fused per task (independent gather chains) ----
__global__ void k_edge(unsigned short* __restrict__ Hd, unsigned short* __restrict__ Hr,
                       const unsigned short* __restrict__ Tbd, const unsigned short* __restrict__ Tbr,
                       const int* __restrict__ off_d, const int* __restrict__ off_s,
                       const unsigned* __restrict__ other_d, const unsigned* __restrict__ other_s,
                       int n_tasks) {
    int lane = threadIdx.x & 63;
    int wave = (blockIdx.x * blockDim.x + threadIdx.x) >> 6;
    int nwaves = (gridDim.x * blockDim.x) >> 6;
    for (int i = wave; i < n_tasks; i += nwaves) {
        int pd = off_d[i], d1 = off_d[i + 1];
        int ps = off_s[i], s1 = off_s[i + 1];
        float cvd = bf2f(Hd[(size_t)i * 64 + lane]);
        float cvr = bf2f(Hr[(size_t)i * 64 + lane]);
        float accd = 0.f, accr = 0.f;
        while (pd + 2 <= d1 && ps + 2 <= s1) {
            unsigned jd0 = other_d[pd], jd1 = other_d[pd + 1];
            unsigned js0 = other_s[ps], js1 = other_s[ps + 1];
            float td0 = bf2f(Tbd[(size_t)jd0 * 64 + lane]);
            float td1 = bf2f(Tbd[(size_t)jd1 * 64 + lane]);
            float tr0 = bf2f(Tbr[(size_t)js0 * 64 + lane]);
            float tr1 = bf2f(Tbr[(size_t)js1 * 64 + lane]);
            accd += leaky(cvd + td0);
            accd += leaky(cvd + td1);
            accr += leaky(cvr + tr0);
            accr += leaky(cvr + tr1);
            pd += 2;
            ps += 2;
        }
        for (; pd + 4 <= d1; pd += 4) {
            float t0 = bf2f(Tbd[(size_t)other_d[pd] * 64 + lane]);
            float t1 = bf2f(Tbd[(size_t)other_d[pd + 1] * 64 + lane]);
            float t2 = bf2f(Tbd[(size_t)other_d[pd + 2] * 64 + lane]);
            float t3 = bf2f(Tbd[(size_t)other_d[pd + 3] * 64 + lane]);
            accd += leaky(cvd + t0);
            accd += leaky(cvd + t1);
            accd += leaky(cvd + t2);
            accd += leaky(cvd + t3);
        }
        for (; pd < d1; ++pd) accd += leaky(cvd + bf2f(Tbd[(size_t)other_d[pd] * 64 + lane]));
        for (; ps + 4 <= s1; ps += 4) {
            float t0 = bf2f(Tbr[(size_t)other_s[ps] * 64 + lane]);
            float t1 = bf2f(Tbr[(size_t)other_s[ps + 1] * 64 + lane]);
            float t2 = bf2f(Tbr[(size_t)other_s[ps + 2] * 64 + lane]);
            float t3 = bf2f(Tbr[(size_t)other_s[ps + 3] * 64 + lane]);
            accr += leaky(cvr + t0);
            accr += leaky(cvr + t1);
            accr += leaky(cvr + t2);
            accr += leaky(cvr + t3);
        }
        for (; ps < s1; ++ps) accr += leaky(cvr + bf2f(Tbr[(size_t)other_s[ps] * 64 + lane]));
        Hd[(size_t)i * 64 + lane] = f2bf(accd);
        Hr[(size_t)i * 64 + lane] = f2bf(accr);
    }
}

// ---------------- layer-2 GEMM + LN + leaky in place: H = LNleaky(bf16(H)@W2 + deg*b2) ----
__global__ void __launch_bounds__(256, 2) k_post(
    unsigned short* __restrict__ Hd, unsigned short* __restrict__ Hr,
    const unsigned short* __restrict__ wfall,
    const float* __restrict__ b2d, const float* __restrict__ b2r,
    const int* __restrict__ deg_d, const int* __restrict__ deg_s,
    const float* __restrict__ dg, const float* __restrict__ db,
    const float* __restrict__ rg, const float* __restrict__ rb,
    int n_rows, int n_tiles) {
    int y = blockIdx.y;
    unsigned short* H = y ? Hr : Hd;
    const unsigned short* wf = wfall + (size_t)(y ? 48 + 32 : 32) * 512;
    const float* b2 = y ? b2r : b2d;
    const int* deg = y ? deg_s : deg_d;
    const float* lng = y ? rg : dg;
    const float* lnb = y ? rb : db;
    int lane = threadIdx.x & 63;
    int r16 = lane & 15, g = lane >> 4;
    int wave = (blockIdx.x * blockDim.x + threadIdx.x) >> 6;
    int nwaves = (gridDim.x * blockDim.x) >> 6;
    short8 w2[2][4][2];
#pragma unroll
    for (int kk = 0; kk < 2; ++kk)
#pragma unroll
        for (int nt = 0; nt < 4; ++nt)
#pragma unroll
            for (int hl = 0; hl < 2; ++hl)
                w2[kk][nt][hl] =
                    *(const short8*)(wf + (size_t)((kk * 4 + nt) * 2 + hl) * 512 + lane * 8);
    float b2v[4], gv[4], bv[4];
#pragma unroll
    for (int nt = 0; nt < 4; ++nt) {
        int c = nt * 16 + r16;
        b2v[nt] = b2[c];
        gv[nt] = lng[c];
        bv[nt] = lnb[c];
    }
    for (int t = wave; t < n_tiles; t += nwaves) {
        int r0 = t * 16;
        int ra = r0 + r16;
        ra = ra < n_rows ? ra : n_rows - 1;
        short8 af[2];
        af[0] = *(const short8*)(H + (size_t)ra * 64 + g * 8);
        af[1] = *(const short8*)(H + (size_t)ra * 64 + 32 + g * 8);
        float degf[4];
#pragma unroll
        for (int q = 0; q < 4; ++q) {
            int r = r0 + g * 4 + q;
            r = r < n_rows ? r : n_rows - 1;
            degf[q] = (float)deg[r];
        }
        f32x4 acc[4];
#pragma unroll
        for (int nt = 0; nt < 4; ++nt)
#pragma unroll
            for (int q = 0; q < 4; ++q) acc[nt][q] = degf[q] * b2v[nt];
#pragma unroll
        for (int kk = 0; kk < 2; ++kk)
#pragma unroll
            for (int nt = 0; nt < 4; ++nt) {
                acc[nt] = __builtin_amdgcn_mfma_f32_16x16x32_bf16(af[kk], w2[kk][nt][0], acc[nt], 0, 0, 0);
                acc[nt] = __builtin_amdgcn_mfma_f32_16x16x32_bf16(af[kk], w2[kk][nt][1], acc[nt], 0, 0, 0);
            }
        // LN across the row (cols spread over r16 x nt), stats via 16-lane-group shuffles
        float s[4], qs[4];
#pragma unroll
        for (int q = 0; q < 4; ++q) {
            s[q] = acc[0][q] + acc[1][q] + acc[2][q] + acc[3][q];
            qs[q] = acc[0][q] * acc[0][q] + acc[1][q] * acc[1][q] +
                    acc[2][q] * acc[2][q] + acc[3][q] * acc[3][q];
        }
#pragma unroll
        for (int o = 1; o <= 8; o <<= 1)
#pragma unroll
            for (int q = 0; q < 4; ++q) {
                s[q] += __shfl_xor(s[q], o, 64);
                qs[q] += __shfl_xor(qs[q], o, 64);
            }
#pragma unroll
        for (int q = 0; q < 4; ++q) {
            float md = s[q] * 0.015625f;
            float rstd = rsqrtf(fmaf(qs[q], 0.015625f, -md * md) + 1e-5f);
            int row = r0 + g * 4 + q;
            if (row < n_rows) {
#pragma unroll
                for (int nt = 0; nt < 4; ++nt)
                    H[(size_t)row * 64 + nt * 16 + r16] =
                        f2bf(leaky(fmaf((acc[nt][q] - md) * rstd, gv[nt], bv[nt])));
            }
        }
    }
}

// ---------------- finalize (MFMA): proj GEMM on LN'd inputs, gsum, candidate ----------
__global__ void __launch_bounds__(256, 2) k_finalize(
    const unsigned short* __restrict__ dep_ln, const unsigned short* __restrict__ rev_ln,
    const unsigned short* __restrict__ pwf, const float* __restrict__ pb,
    float* __restrict__ out, float* __restrict__ gsum, int n_rows, int n_tiles) {
    __shared__ float red[4][64];
    int lane = threadIdx.x & 63;
    int wid = threadIdx.x >> 6;
    int r16 = lane & 15, g = lane >> 4;
    int wave = (blockIdx.x * blockDim.x + threadIdx.x) >> 6;
    int nwaves = (gridDim.x * blockDim.x) >> 6;

    short8 wf[4][4][2];
#pragma unroll
    for (int kk = 0; kk < 4; ++kk)
#pragma unroll
        for (int nt = 0; nt < 4; ++nt)
#pragma unroll
            for (int hl = 0; hl < 2; ++hl)
                wf[kk][nt][hl] =
                    *(const short8*)(pwf + (size_t)((kk * 4 + nt) * 2 + hl) * 512 + lane * 8);

    float b2v[4];
#pragma unroll
    for (int nt = 0; nt < 4; ++nt) b2v[nt] = pb[nt * 16 + r16];
    float gacc[4] = {0.f, 0.f, 0.f, 0.f};

    for (int t = wave; t < n_tiles; t += nwaves) {
        int r0 = t * 16;
        int ra = r0 + r16;
        ra = ra < n_rows ? ra : n_rows - 1;
        short8 af[4];
        af[0] = *(const short8*)(dep_ln + (size_t)ra * 64 + g * 8);
        af[1] = *(const short8*)(dep_ln + (size_t)ra * 64 + 32 + g * 8);
        af[2] = *(const short8*)(rev_ln + (size_t)ra * 64 + g * 8);
        af[3] = *(const short8*)(rev_ln + (size_t)ra * 64 + 32 + g * 8);

        f32x4 acc[4];
#pragma unroll
        for (int nt = 0; nt < 4; ++nt) acc[nt] = (f32x4){b2v[nt], b2v[nt], b2v[nt], b2v[nt]};
#pragma unroll
        for (int kk = 0; kk < 4; ++kk)
#pragma unroll
            for (int nt = 0; nt < 4; ++nt) {
                acc[nt] = __builtin_amdgcn_mfma_f32_16x16x32_bf16(af[kk], wf[kk][nt][0], acc[nt], 0, 0, 0);
                acc[nt] = __builtin_amdgcn_mfma_f32_16x16x32_bf16(af[kk], wf[kk][nt][1], acc[nt], 0, 0, 0);
            }
#pragma unroll
        for (int nt = 0; nt < 4; ++nt)
#pragma unroll
            for (int q = 0; q < 4; ++q) {
                float tf = leaky(acc[nt][q]);
                int grow = r0 + g * 4 + q;
                if (grow < n_rows) gacc[nt] += tf;
                if (grow == 0) out[64 + nt * 16 + r16] = tf;
            }
    }
#pragma unroll
    for (int nt = 0; nt < 4; ++nt) {
        gacc[nt] += __shfl_xor(gacc[nt], 16, 64);
        gacc[nt] += __shfl_xor(gacc[nt], 32, 64);
    }
    if (g == 0) {
#pragma unroll
        for (int nt = 0; nt < 4; ++nt) red[wid][nt * 16 + r16] = gacc[nt];
    }
    __syncthreads();
    if (threadIdx.x < 64) {
        float ssum = red[0][threadIdx.x] + red[1][threadIdx.x] +
                     red[2][threadIdx.x] + red[3][threadIdx.x];
        atomicAdd(&gsum[threadIdx.x], ssum);
    }
}

// ---------------- tail ----------------
__global__ void k_tail(const float* __restrict__ gsum, const int* __restrict__ counts,
                       const float* __restrict__ devx, const float* __restrict__ timex,
                       const float* __restrict__ dW, const float* __restrict__ dB,
                       float* __restrict__ out) {
    int j = threadIdx.x;
    if (j >= 64) return;
    int c = counts[0];
    if (c < 1) c = 1;
    out[j] = gsum[j] / (float)c;
    float t = timex[0] * 1e-5f;
    float acc = dB[j];
    for (int k = 0; k < 96; ++k) acc = fmaf(devx[k], dW[k * 64 + j], acc);
    acc = fmaf(t, dW[96 * 64 + j], acc);
    out[128 + j] = leaky(acc);
}

extern "C" void kernel_launch(void* const* d_in, const int* in_sizes, int n_in,
                              void* d_out, int out_size, void* d_ws, size_t ws_size,
                              hipStream_t stream) {
    const float* data_x    = (const float*)d_in[0];
    const float* tasks_x   = (const float*)d_in[1];
    const float* devices_x = (const float*)d_in[2];
    const float* time_x    = (const float*)d_in[3];
    const int*   dt_src    = (const int*)d_in[4];
    const int*   dt_dst    = (const int*)d_in[5];
    const int*   tt_src    = (const int*)d_in[6];
    const int*   tt_dst    = (const int*)d_in[7];
    const int*   counts    = (const int*)d_in[8];
    const float* gc_W_rel  = (const float*)d_in[9];
    const float* gc_b_rel  = (const float*)d_in[10];
    const float* gc_W_root = (const float*)d_in[11];
    const float* gc_ln_g   = (const float*)d_in[12];
    const float* gc_ln_b   = (const float*)d_in[13];
    const float* dep_W1    = (const float*)d_in[14];
    const float* dep_b1    = (const float*)d_in[15];
    const float* dep_W2    = (const float*)d_in[16];
    const float* dep_b2    = (const float*)d_in[17];
    const float* dep_ln_g  = (const float*)d_in[18];
    const float* dep_ln_b  = (const float*)d_in[19];
    const float* rev_W1    = (const float*)d_in[20];
    const float* rev_b1    = (const float*)d_in[21];
    const float* rev_W2    = (const float*)d_in[22];
    const float* rev_b2    = (const float*)d_in[23];
    const float* rev_ln_g  = (const float*)d_in[24];
    const float* rev_ln_b  = (const float*)d_in[25];
    const float* dev_W     = (const float*)d_in[26];
    const float* dev_b     = (const float*)d_in[27];
    const float* proj_W    = (const float*)d_in[28];
    const float* proj_b    = (const float*)d_in[29];

    int n_tasks = in_sizes[1] / 12;
    int n_dt = in_sizes[4];
    int n_tt = in_sizes[6];
    int n_tiles = (n_tasks + 15) / 16;
    int nbuk = (n_tasks + BUCKET - 1) / BUCKET;
    int nscan = nbuk * NB3;

    char* ws = (char*)d_ws;
    size_t off = 0;
    auto alloc = [&](size_t bytes) {
        char* p = ws + off;
        off += (bytes + 255) & ~(size_t)255;
        return p;
    };
    unsigned short* xh    = (unsigned short*)alloc((size_t)n_tasks * 64 * 2);
    unsigned short* Hd    = (unsigned short*)alloc((size_t)n_tasks * 64 * 2);
    unsigned short* Hr    = (unsigned short*)alloc((size_t)n_tasks * 64 * 2);
    unsigned short* Tbd   = (unsigned short*)alloc((size_t)n_tasks * 64 * 2);
    unsigned short* Tbr   = (unsigned short*)alloc((size_t)n_tasks * 64 * 2);
    int* cnt_d            = (int*)alloc((size_t)nscan * 4);
    int* cnt_s            = (int*)alloc((size_t)nscan * 4);
    int* cnt_t            = (int*)alloc((size_t)nscan * 4);
    int* base_d           = (int*)alloc((size_t)nscan * 4);
    int* base_s           = (int*)alloc((size_t)nscan * 4);
    int* base_t           = (int*)alloc((size_t)nscan * 4);
    unsigned* packed_d    = (unsigned*)alloc((size_t)n_tt * 4);
    unsigned* packed_s    = (unsigned*)alloc((size_t)n_tt * 4);
    unsigned* packed_t    = (unsigned*)alloc((size_t)n_dt * 4);
    unsigned* other_d     = (unsigned*)alloc((size_t)n_tt * 4);
    unsigned* other_s     = (unsigned*)alloc((size_t)n_tt * 4);
    int* off_d            = (int*)alloc(((size_t)n_tasks + 1) * 4);
    int* off_s            = (int*)alloc(((size_t)n_tasks + 1) * 4);
    int* deg_d            = (int*)alloc((size_t)n_tasks * 4);
    int* deg_s            = (int*)alloc((size_t)n_tasks * 4);
    int* bsum             = (int*)alloc(3 * NB_SCAN * 4);
    float* gsum           = (float*)alloc(64 * 4);
    unsigned short* wfrag = (unsigned short*)alloc((size_t)128 * 512 * 2);

    k_prepw<<<20, 64, 0, stream>>>(dep_W1, dep_W2, rev_W1, rev_W2, proj_W, wfrag, gsum);

    k_bhist<<<dim3(NB3, 2), 256, 0, stream>>>(tt_src, tt_dst, dt_dst,
                                              cnt_d, cnt_s, cnt_t, n_tt, n_dt, nbuk);
    k_scanA<<<dim3(NB_SCAN, 3), 256, 0, stream>>>(cnt_d, cnt_s, cnt_t, bsum, nscan);
    k_scanC<<<dim3(NB_SCAN, 3), 256, 0, stream>>>(cnt_d, cnt_s, cnt_t, bsum,
                                                  base_d, base_s, base_t, nscan);
    k_bdump<<<dim3(NB3, 2), 256, 0, stream>>>(tt_src, tt_dst, dt_src, dt_dst,
                                              base_d, base_s, base_t,
                                              packed_d, packed_s, packed_t, n_tt, n_dt, nbuk);
    k_bcsr<<<dim3(nbuk, 2), 256, 0, stream>>>(packed_d, packed_s, base_d, base_s,
                                              other_d, other_s, off_d, off_s,
                                              deg_d, deg_s, n_tt, n_tasks, nbuk);

    k_aggfused<<<nbuk, 256, 0, stream>>>(data_x, packed_t, base_t, tasks_x,
                                         gc_W_rel, gc_b_rel, gc_W_root,
                                         gc_ln_g, gc_ln_b, xh, n_dt, n_tasks, nbuk);

    k_ct<<<dim3(2048, 2), 256, 0, stream>>>(xh, wfrag, dep_b1, rev_b1, Hd, Hr, Tbd, Tbr,
                                            n_tasks, n_tiles);
    k_edge<<<4096, 256, 0, stream>>>(Hd, Hr, Tbd, Tbr, off_d, off_s,
                                     other_d, other_s, n_tasks);
    k_post<<<dim3(2048, 2), 256, 0, stream>>>(Hd, Hr, wfrag, dep_b2, rev_b2,
                                              deg_d, deg_s,
                                              dep_ln_g, dep_ln_b, rev_ln_g, rev_ln_b,
                                              n_tasks, n_tiles);

    k_finalize<<<2048, 256, 0, stream>>>(Hd, Hr, wfrag + (size_t)96 * 512, proj_b,
                                         (float*)d_out, gsum, n_tasks, n_tiles);
    k_tail<<<1, 64, 0, stream>>>(gsum, counts, devices_x, time_x, dev_W, dev_b, (float*)d_out);
}